// Round 1
// baseline (3243.789 us; speedup 1.0000x reference)
//
#include <hip/hip_runtime.h>

#define DIM 384
#define PATCHES 196
#define HID 1536
#define NBLK 24
#define NPAD 224                    // K-padded patch count for attn GEMM
#define XROWS (64 * PATCHES)        // 12544
#define BDCOLS (64 * DIM)           // 24576
#define XELEMS (XROWS * DIM)        // 4816896

typedef __attribute__((ext_vector_type(8))) short s8v;
typedef __attribute__((ext_vector_type(4))) float f4v;

__device__ __forceinline__ short f2bf(float f) {
  unsigned u = __float_as_uint(f);
  u += 0x7FFFu + ((u >> 16) & 1u);   // RNE f32 -> bf16
  return (short)(u >> 16);
}

__device__ __forceinline__ void gload_lds16(const short* g, short* l) {
  __builtin_amdgcn_global_load_lds((const __attribute__((address_space(1))) void*)g,
                                   (__attribute__((address_space(3))) void*)l, 16, 0, 0);
}

// ---------------- absmax (per-tensor) ----------------
__global__ __launch_bounds__(256)
void absmax_k(const float* __restrict__ src, int per, int blocks_per,
              unsigned* __restrict__ out) {
  int tens = blockIdx.x / blocks_per;
  int sl = blockIdx.x - tens * blocks_per;
  const float* p = src + (long)tens * per;
  float m = 0.f;
  for (int i = sl * 256 + threadIdx.x; i < per; i += blocks_per * 256)
    m = fmaxf(m, fabsf(p[i]));
  __shared__ float red[256];
  red[threadIdx.x] = m;
  __syncthreads();
  for (int s = 128; s > 0; s >>= 1) {
    if ((int)threadIdx.x < s) red[threadIdx.x] = fmaxf(red[threadIdx.x], red[threadIdx.x + s]);
    __syncthreads();
  }
  if (threadIdx.x == 0) atomicMax(out + tens, __float_as_uint(red[0]));
}

// ---------------- quantize (fake-quant, bit-exact fq, then bf16 store) ----------------
__global__ __launch_bounds__(256)
void quant_w(const float* __restrict__ w, short* __restrict__ q,
             const unsigned* __restrict__ sc, int per, int total) {
  int i = blockIdx.x * 256 + threadIdx.x;
  if (i >= total) return;
  int tens = i / per;
  float s = __uint_as_float(sc[tens]) / 127.0f + 1e-8f;
  float v = rintf(w[i] / s);
  v = fminf(fmaxf(v, -128.0f), 127.0f) * s;
  q[i] = f2bf(v);
}

__global__ __launch_bounds__(256)
void quant_attn(const float* __restrict__ w, short* __restrict__ q,
                const unsigned* __restrict__ sc) {
  int i = blockIdx.x * 256 + threadIdx.x;       // over 24*196*224
  if (i >= NBLK * PATCHES * NPAD) return;
  int col = i % NPAD;
  int rt = i / NPAD;
  int row = rt % PATCHES;
  int tens = rt / PATCHES;
  float outv = 0.f;
  if (col < PATCHES) {
    float s = __uint_as_float(sc[tens]) / 127.0f + 1e-8f;
    float v = rintf(w[tens * PATCHES * PATCHES + row * PATCHES + col] / s);
    outv = fminf(fmaxf(v, -128.0f), 127.0f) * s;
  }
  q[i] = f2bf(outv);
}

__global__ __launch_bounds__(256)
void quant_head(const float* __restrict__ w, float* __restrict__ q,
                const unsigned* __restrict__ sc) {
  int i = blockIdx.x * 256 + threadIdx.x;
  if (i >= 1000 * DIM) return;
  float s = __uint_as_float(sc[0]) / 127.0f + 1e-8f;
  float v = rintf(w[i] / s);
  q[i] = fminf(fmaxf(v, -128.0f), 127.0f) * s;
}

// ---------------- im2col + bf16 cast (stride-16 16x16 patches: no overlap) ----------------
__global__ __launch_bounds__(256)
void im2col_k(const float* __restrict__ x, short* __restrict__ Xa) {
  int idx = blockIdx.x * 256 + threadIdx.x;     // each handles 4 elems
  if (idx >= XROWS * 768 / 4) return;
  int e = idx << 2;
  int r = e / 768, k = e - r * 768;
  int b = r / PATCHES, p = r - b * PATCHES;
  int c = k >> 8, rem = k & 255, ii = rem >> 4, j = rem & 15;
  int ph = p / 14, pw = p - ph * 14;
  const float4 v = *(const float4*)(x + (b * 3 + c) * 50176 + (ph * 16 + ii) * 224 + pw * 16 + j);
  short2* o = (short2*)(Xa + e);
  o[0] = make_short2(f2bf(v.x), f2bf(v.y));
  o[1] = make_short2(f2bf(v.z), f2bf(v.w));
}

// ---------------- norm1 + cast + transpose: Yt[(b,d)][p] = bf16(X[b,p,d]*a+b), p-padded to 224 ----
__global__ __launch_bounds__(256)
void normcast_t(const float* __restrict__ X, const float* __restrict__ a1,
                const float* __restrict__ b1, short* __restrict__ Yt) {
  __shared__ short lds[32][72];
  const int t = threadIdx.x;
  const int p0 = blockIdx.y << 5, c0 = blockIdx.x << 6;
  const int cl = t & 63, pl = t >> 6;
  const int c = c0 + cl;
  const int b = c / DIM, d = c - b * DIM;
  const float av = a1[d], bv = b1[d];
#pragma unroll
  for (int i = 0; i < 8; ++i) {
    int p = p0 + pl + (i << 2);
    float xv = 0.f;
    if (p < PATCHES) xv = X[b * (PATCHES * DIM) + p * DIM + d] * av + bv;
    lds[pl + (i << 2)][cl] = f2bf(xv);
  }
  __syncthreads();
  const int r2 = t >> 2, q2 = t & 3;
  short2* o = (short2*)(Yt + (c0 + r2) * NPAD + p0);
#pragma unroll
  for (int i = 0; i < 4; ++i) {
    int k = q2 + (i << 2);
    short2 v;
    v.x = lds[2 * k][r2];
    v.y = lds[2 * k + 1][r2];
    o[k] = v;
  }
}

// ---------------- GEMM C = A * B^T  (A [M][lda] bf16, B [N][ldb] bf16, both K-contiguous) ----
// EPI 0: conv   -> X[r*384+c] = acc + bias[c]
// EPI 1: attn   -> xn = X + g1[d]*(acc + bias[r]); X = xn; Y2 = bf16(xn*n2a+n2b)   (cols=(b,d))
// EPI 2: mlp1   -> H[r*1536+c] = bf16(gelu(acc + bias[c]))
// EPI 3: mlp2   -> X[r*384+c] += g2[c]*(acc + bias[c])
template <int EPI>
__global__ __launch_bounds__(256)
void gemm_bt(const short* __restrict__ A, int lda, int Mlim,
             const short* __restrict__ B, int ldb, int K,
             float* __restrict__ Xres, short* __restrict__ OutB,
             const float* __restrict__ bias, const float* __restrict__ gamma,
             const float* __restrict__ n2a, const float* __restrict__ n2b) {
  __shared__ short ldsA[128 * 32];
  __shared__ short ldsB[128 * 32];
  const int t = threadIdx.x;
  const int lane = t & 63;
  const int wid = t >> 6;
  const int wr = wid >> 1, wc = wid & 1;
  const int m0 = blockIdx.y * 128, n0 = blockIdx.x * 128;

  f4v acc[4][4];
#pragma unroll
  for (int m = 0; m < 4; ++m)
#pragma unroll
    for (int n = 0; n < 4; ++n) acc[m][n] = (f4v){0.f, 0.f, 0.f, 0.f};

  const int sr = t >> 2;            // staging row within 64-row half
  const int scol = (t & 3) << 3;    // staging col (x8 bf16)
  const int wbase = (t & ~63) * 8;  // LDS wave base in shorts (HW adds lane*16B)

  const int nk = K >> 5;
  for (int kt = 0; kt < nk; ++kt) {
    const int kb = (kt << 5) + scol;
    int r0 = m0 + sr;      if (r0 >= Mlim) r0 = Mlim - 1;
    int r1 = m0 + 64 + sr; if (r1 >= Mlim) r1 = Mlim - 1;
    gload_lds16(A + r0 * lda + kb, ldsA + wbase);
    gload_lds16(A + r1 * lda + kb, ldsA + 2048 + wbase);
    gload_lds16(B + (n0 + sr) * ldb + kb, ldsB + wbase);
    gload_lds16(B + (n0 + 64 + sr) * ldb + kb, ldsB + 2048 + wbase);
    __syncthreads();
    const short* pa = ldsA + ((wr << 6) + (lane & 15)) * 32 + ((lane >> 4) << 3);
    const short* pb = ldsB + ((wc << 6) + (lane & 15)) * 32 + ((lane >> 4) << 3);
    s8v af[4], bfr[4];
#pragma unroll
    for (int m = 0; m < 4; ++m) af[m] = *(const s8v*)(pa + m * 512);
#pragma unroll
    for (int n = 0; n < 4; ++n) bfr[n] = *(const s8v*)(pb + n * 512);
#pragma unroll
    for (int m = 0; m < 4; ++m)
#pragma unroll
      for (int n = 0; n < 4; ++n)
        acc[m][n] = __builtin_amdgcn_mfma_f32_16x16x32_bf16(af[m], bfr[n], acc[m][n], 0, 0, 0);
    __syncthreads();
  }

  const int rbase = m0 + (wr << 6) + ((lane >> 4) << 2);
  const int cbase = n0 + (wc << 6) + (lane & 15);
#pragma unroll
  for (int m = 0; m < 4; ++m) {
#pragma unroll
    for (int n = 0; n < 4; ++n) {
      int col = cbase + n * 16;
#pragma unroll
      for (int j = 0; j < 4; ++j) {
        int r = rbase + m * 16 + j;
        float v = acc[m][n][j];
        if (EPI == 0) {
          Xres[r * DIM + col] = v + bias[col];
        } else if (EPI == 1) {
          if (r < Mlim) {
            int b = col / DIM, d = col - b * DIM;
            int addr = b * (PATCHES * DIM) + r * DIM + d;
            float xn = Xres[addr] + gamma[d] * (v + bias[r]);
            Xres[addr] = xn;
            OutB[addr] = f2bf(xn * n2a[d] + n2b[d]);
          }
        } else if (EPI == 2) {
          float xg = v + bias[col];
          float g = 0.5f * xg * (1.0f + erff(xg * 0.70710678118654752f));
          OutB[r * HID + col] = f2bf(g);
        } else {
          int addr = r * DIM + col;
          Xres[addr] += gamma[col] * (v + bias[col]);
        }
      }
    }
  }
}

// ---------------- final affine norm + mean pool ----------------
__global__ __launch_bounds__(384)
void poolnorm(const float* __restrict__ X, const float* __restrict__ na,
              const float* __restrict__ nb, float* __restrict__ pooled) {
  int b = blockIdx.x, d = threadIdx.x;
  const float* p = X + b * (PATCHES * DIM) + d;
  float s = 0.f;
  for (int i = 0; i < PATCHES; ++i) s += p[i * DIM];
  pooled[b * DIM + d] = (s * (1.0f / 196.0f)) * na[d] + nb[d];
}

// ---------------- head: out[b,n] = pooled[b,:] . Whq[n,:] + hb[n] (fp32) ----------------
__global__ __launch_bounds__(256)
void head_k(const float* __restrict__ pooled, const float* __restrict__ Whq,
            const float* __restrict__ hb, float* __restrict__ out) {
  __shared__ float pl[DIM];
  int b = blockIdx.x, t = threadIdx.x;
  if (t < 192) {
    pl[t] = pooled[b * DIM + t];
    pl[t + 192] = pooled[b * DIM + t + 192];
  }
  __syncthreads();
  for (int n = t; n < 1000; n += 256) {
    const float4* w = (const float4*)(Whq + n * DIM);
    float s = 0.f;
#pragma unroll 4
    for (int i = 0; i < DIM / 4; ++i) {
      float4 wv = w[i];
      s += pl[4 * i] * wv.x + pl[4 * i + 1] * wv.y + pl[4 * i + 2] * wv.z + pl[4 * i + 3] * wv.w;
    }
    out[b * 1000 + n] = s + hb[n];
  }
}

extern "C" void kernel_launch(void* const* d_in, const int* in_sizes, int n_in,
                              void* d_out, int out_size, void* d_ws, size_t ws_size,
                              hipStream_t stream) {
  const float* x       = (const float*)d_in[0];
  const float* conv_w  = (const float*)d_in[1];
  const float* conv_b  = (const float*)d_in[2];
  const float* norm1_a = (const float*)d_in[3];
  const float* norm1_b = (const float*)d_in[4];
  const float* attn_w  = (const float*)d_in[5];
  const float* attn_b  = (const float*)d_in[6];
  const float* gamma1  = (const float*)d_in[7];
  const float* norm2_a = (const float*)d_in[8];
  const float* norm2_b = (const float*)d_in[9];
  const float* mlp_w1  = (const float*)d_in[10];
  const float* mlp_b1  = (const float*)d_in[11];
  const float* mlp_w2  = (const float*)d_in[12];
  const float* mlp_b2  = (const float*)d_in[13];
  const float* gamma2  = (const float*)d_in[14];
  const float* norm_a  = (const float*)d_in[15];
  const float* norm_b  = (const float*)d_in[16];
  const float* head_w  = (const float*)d_in[17];
  const float* head_b  = (const float*)d_in[18];
  (void)in_sizes; (void)n_in; (void)out_size; (void)ws_size;

  char* ws = (char*)d_ws;
  size_t off = 0;
  auto alloc = [&](size_t bytes) {
    off = (off + 255) & ~(size_t)255;
    void* p = ws + off;
    off += bytes;
    return p;
  };
  unsigned* scales = (unsigned*)alloc(74 * 4);
  short* conv_wq = (short*)alloc((size_t)DIM * 768 * 2);
  short* attn_wq = (short*)alloc((size_t)NBLK * PATCHES * NPAD * 2);
  short* w1q     = (short*)alloc((size_t)NBLK * HID * DIM * 2);
  short* w2q     = (short*)alloc((size_t)NBLK * DIM * HID * 2);
  float* headq   = (float*)alloc((size_t)1000 * DIM * 4);
  float* X       = (float*)alloc((size_t)XELEMS * 4);
  short* Yt      = (short*)alloc((size_t)BDCOLS * NPAD * 2);
  short* Y2      = (short*)alloc((size_t)XELEMS * 2);
  short* H       = (short*)alloc((size_t)XROWS * HID * 2);
  float* pooled  = (float*)alloc((size_t)64 * DIM * 4);
  short* Xa = H;  // alias: im2col buffer [12544][768] bf16, dead before H is first written

  hipMemsetAsync(scales, 0, 74 * 4, stream);
  // scale slots: [0]=conv, [1]=head, [2..25]=attn, [26..49]=w1, [50..73]=w2
  absmax_k<<<16, 256, 0, stream>>>(conv_w, DIM * 768, 16, scales + 0);
  absmax_k<<<16, 256, 0, stream>>>(head_w, 1000 * DIM, 16, scales + 1);
  absmax_k<<<NBLK * 4, 256, 0, stream>>>(attn_w, PATCHES * PATCHES, 4, scales + 2);
  absmax_k<<<NBLK * 16, 256, 0, stream>>>(mlp_w1, HID * DIM, 16, scales + 26);
  absmax_k<<<NBLK * 16, 256, 0, stream>>>(mlp_w2, DIM * HID, 16, scales + 50);

  quant_w<<<(DIM * 768) / 256, 256, 0, stream>>>(conv_w, conv_wq, scales + 0, DIM * 768, DIM * 768);
  quant_w<<<(NBLK * HID * DIM) / 256, 256, 0, stream>>>(mlp_w1, w1q, scales + 26, HID * DIM, NBLK * HID * DIM);
  quant_w<<<(NBLK * HID * DIM) / 256, 256, 0, stream>>>(mlp_w2, w2q, scales + 50, DIM * HID, NBLK * DIM * HID);
  quant_attn<<<(NBLK * PATCHES * NPAD) / 256, 256, 0, stream>>>(attn_w, attn_wq, scales + 2);
  quant_head<<<(1000 * DIM + 255) / 256, 256, 0, stream>>>(head_w, headq, scales + 1);

  im2col_k<<<(XROWS * 768 / 4) / 256, 256, 0, stream>>>(x, Xa);
  gemm_bt<0><<<dim3(3, 98), 256, 0, stream>>>(Xa, 768, XROWS, conv_wq, 768, 768,
                                              X, nullptr, conv_b, nullptr, nullptr, nullptr);

  for (int blk = 0; blk < NBLK; ++blk) {
    normcast_t<<<dim3(BDCOLS / 64, 7), 256, 0, stream>>>(X, norm1_a + blk * DIM,
                                                         norm1_b + blk * DIM, Yt);
    gemm_bt<1><<<dim3(BDCOLS / 128, 2), 256, 0, stream>>>(
        attn_wq + blk * PATCHES * NPAD, NPAD, PATCHES, Yt, NPAD, NPAD,
        X, Y2, attn_b + blk * PATCHES, gamma1 + blk * DIM,
        norm2_a + blk * DIM, norm2_b + blk * DIM);
    gemm_bt<2><<<dim3(HID / 128, XROWS / 128), 256, 0, stream>>>(
        Y2, DIM, XROWS, w1q + (size_t)blk * HID * DIM, DIM, DIM,
        nullptr, H, mlp_b1 + blk * HID, nullptr, nullptr, nullptr);
    gemm_bt<3><<<dim3(DIM / 128, XROWS / 128), 256, 0, stream>>>(
        H, HID, XROWS, w2q + (size_t)blk * DIM * HID, HID, HID,
        X, nullptr, mlp_b2 + blk * DIM, gamma2 + blk * DIM, nullptr, nullptr);
  }

  poolnorm<<<64, 384, 0, stream>>>(X, norm_a, norm_b, pooled);
  head_k<<<64, 256, 0, stream>>>(pooled, headq, head_b, (float*)d_out);
}

// Round 2
// 3037.590 us; speedup vs baseline: 1.0679x; 1.0679x over previous
//
#include <hip/hip_runtime.h>

#define DIM 384
#define PATCHES 196
#define HID 1536
#define NBLK 24
#define NPAD 224                    // K-padded patch count for attn GEMM
#define XROWS (64 * PATCHES)        // 12544
#define BDCOLS (64 * DIM)           // 24576
#define XELEMS (XROWS * DIM)        // 4816896
#define ESTRIDE 132                 // epilogue LDS stage row stride (floats), 132%32=4 -> conflict-free

typedef __attribute__((ext_vector_type(8))) short s8v;
typedef __attribute__((ext_vector_type(4))) float f4v;

__device__ __forceinline__ short f2bf(float f) {
  unsigned u = __float_as_uint(f);
  u += 0x7FFFu + ((u >> 16) & 1u);   // RNE f32 -> bf16
  return (short)(u >> 16);
}

__device__ __forceinline__ float gelu_f(float x) {
  // tanh-approx GELU: x * sigmoid(2*0.7978845608*(x + 0.044715 x^3))
  float u2 = 1.5957691216f * (x + 0.044715f * x * x * x);
  return x / (1.0f + __expf(-u2));
}

__device__ __forceinline__ void gload_lds16(const short* g, short* l) {
  __builtin_amdgcn_global_load_lds((const __attribute__((address_space(1))) void*)g,
                                   (__attribute__((address_space(3))) void*)l, 16, 0, 0);
}

// ---------------- absmax (per-tensor) ----------------
__global__ __launch_bounds__(256)
void absmax_k(const float* __restrict__ src, int per, int blocks_per,
              unsigned* __restrict__ out) {
  int tens = blockIdx.x / blocks_per;
  int sl = blockIdx.x - tens * blocks_per;
  const float* p = src + (long)tens * per;
  float m = 0.f;
  for (int i = sl * 256 + threadIdx.x; i < per; i += blocks_per * 256)
    m = fmaxf(m, fabsf(p[i]));
  __shared__ float red[256];
  red[threadIdx.x] = m;
  __syncthreads();
  for (int s = 128; s > 0; s >>= 1) {
    if ((int)threadIdx.x < s) red[threadIdx.x] = fmaxf(red[threadIdx.x], red[threadIdx.x + s]);
    __syncthreads();
  }
  if (threadIdx.x == 0) atomicMax(out + tens, __float_as_uint(red[0]));
}

// ---------------- quantize (fake-quant, bit-exact fq, then bf16 store) ----------------
__global__ __launch_bounds__(256)
void quant_w(const float* __restrict__ w, short* __restrict__ q,
             const unsigned* __restrict__ sc, int per, int total) {
  int i = blockIdx.x * 256 + threadIdx.x;
  if (i >= total) return;
  int tens = i / per;
  float s = __uint_as_float(sc[tens]) / 127.0f + 1e-8f;
  float v = rintf(w[i] / s);
  v = fminf(fmaxf(v, -128.0f), 127.0f) * s;
  q[i] = f2bf(v);
}

__global__ __launch_bounds__(256)
void quant_attn(const float* __restrict__ w, short* __restrict__ q,
                const unsigned* __restrict__ sc) {
  int i = blockIdx.x * 256 + threadIdx.x;       // over 24*196*224
  if (i >= NBLK * PATCHES * NPAD) return;
  int col = i % NPAD;
  int rt = i / NPAD;
  int row = rt % PATCHES;
  int tens = rt / PATCHES;
  float outv = 0.f;
  if (col < PATCHES) {
    float s = __uint_as_float(sc[tens]) / 127.0f + 1e-8f;
    float v = rintf(w[tens * PATCHES * PATCHES + row * PATCHES + col] / s);
    outv = fminf(fmaxf(v, -128.0f), 127.0f) * s;
  }
  q[i] = f2bf(outv);
}

__global__ __launch_bounds__(256)
void quant_head(const float* __restrict__ w, float* __restrict__ q,
                const unsigned* __restrict__ sc) {
  int i = blockIdx.x * 256 + threadIdx.x;
  if (i >= 1000 * DIM) return;
  float s = __uint_as_float(sc[0]) / 127.0f + 1e-8f;
  float v = rintf(w[i] / s);
  q[i] = fminf(fmaxf(v, -128.0f), 127.0f) * s;
}

// ---------------- im2col + bf16 cast (stride-16 16x16 patches: no overlap) ----------------
__global__ __launch_bounds__(256)
void im2col_k(const float* __restrict__ x, short* __restrict__ Xa) {
  int idx = blockIdx.x * 256 + threadIdx.x;     // each handles 4 elems
  if (idx >= XROWS * 768 / 4) return;
  int e = idx << 2;
  int r = e / 768, k = e - r * 768;
  int b = r / PATCHES, p = r - b * PATCHES;
  int c = k >> 8, rem = k & 255, ii = rem >> 4, j = rem & 15;
  int ph = p / 14, pw = p - ph * 14;
  const float4 v = *(const float4*)(x + (b * 3 + c) * 50176 + (ph * 16 + ii) * 224 + pw * 16 + j);
  short2* o = (short2*)(Xa + e);
  o[0] = make_short2(f2bf(v.x), f2bf(v.y));
  o[1] = make_short2(f2bf(v.z), f2bf(v.w));
}

// ---------------- norm1 + cast + transpose: Yt[(b,d)][p] = bf16(X[b,p,d]*a+b), p-padded to 224 ----
__global__ __launch_bounds__(256)
void normcast_t(const float* __restrict__ X, const float* __restrict__ a1,
                const float* __restrict__ b1, short* __restrict__ Yt) {
  __shared__ short lds[32][72];
  const int t = threadIdx.x;
  const int p0 = blockIdx.y << 5, c0 = blockIdx.x << 6;
  const int cl = t & 63, pl = t >> 6;
  const int c = c0 + cl;
  const int b = c / DIM, d = c - b * DIM;
  const float av = a1[d], bv = b1[d];
#pragma unroll
  for (int i = 0; i < 8; ++i) {
    int p = p0 + pl + (i << 2);
    float xv = 0.f;
    if (p < PATCHES) xv = X[b * (PATCHES * DIM) + p * DIM + d] * av + bv;
    lds[pl + (i << 2)][cl] = f2bf(xv);
  }
  __syncthreads();
  const int r2 = t >> 2, q2 = t & 3;
  short2* o = (short2*)(Yt + (c0 + r2) * NPAD + p0);
#pragma unroll
  for (int i = 0; i < 4; ++i) {
    int k = q2 + (i << 2);
    short2 v;
    v.x = lds[2 * k][r2];
    v.y = lds[2 * k + 1][r2];
    o[k] = v;
  }
}

// ---------------- GEMM C = A * B^T  (A [M][lda] bf16, B [N][ldb] bf16, both K-contiguous) ----
// Tile: TM x 128, 4 waves. TM=128: wave=64x64 (4x4 frags). TM=64: wave=32x64 (2x4 frags).
// Epilogue: per 16-row fragment group, stage fp32 acc in LDS (stride 132), re-read
// coalesced (16 consecutive cols/thread), apply EPI op with vectorized global access.
// EPI 0: conv   -> X[r*384+c] = acc + bias[c]
// EPI 1: attn   -> xn = X + g1[d]*(acc + bias[r]); X = xn; Y2 = bf16(xn*n2a+n2b)   (cols=(b,d))
// EPI 2: mlp1   -> H[r*1536+c] = bf16(gelu(acc + bias[c]))
// EPI 3: mlp2   -> X[r*384+c] += g2[c]*(acc + bias[c])
template <int EPI, int TM>
__global__ __launch_bounds__(256)
void gemm2(const short* __restrict__ A, int lda, int Mlim,
           const short* __restrict__ B, int ldb, int K,
           float* __restrict__ Xres, short* __restrict__ OutB,
           const float* __restrict__ bias, const float* __restrict__ gamma,
           const float* __restrict__ n2a, const float* __restrict__ n2b) {
  constexpr int MF = TM / 32;                 // m-fragments per wave
  __shared__ char smem[32 * ESTRIDE * 4];     // 16896 B; unioned K-loop tiles + epilogue stage
  short* ldsA = (short*)smem;                 // [TM][32]
  short* ldsB = ldsA + TM * 32;               // [128][32]
  float* S = (float*)smem;                    // [32][ESTRIDE]

  const int t = threadIdx.x;
  const int lane = t & 63;
  const int wid = t >> 6;
  const int wr = wid >> 1, wc = wid & 1;
  const int m0 = blockIdx.y * TM, n0 = blockIdx.x * 128;

  f4v acc[MF][4];
#pragma unroll
  for (int m = 0; m < MF; ++m)
#pragma unroll
    for (int n = 0; n < 4; ++n) acc[m][n] = (f4v){0.f, 0.f, 0.f, 0.f};

  const int sr = t >> 2;            // staging row within 64-row half
  const int scol = (t & 3) << 3;    // staging col (x8 bf16)
  const int wbase = (t & ~63) * 8;  // LDS wave base in shorts (HW adds lane*16B)

  const int nk = K >> 5;
  for (int kt = 0; kt < nk; ++kt) {
    const int kb = (kt << 5) + scol;
#pragma unroll
    for (int h = 0; h < TM / 64; ++h) {
      int r = m0 + h * 64 + sr;
      if (r >= Mlim) r = Mlim - 1;
      gload_lds16(A + r * lda + kb, ldsA + h * 2048 + wbase);
    }
    gload_lds16(B + (n0 + sr) * ldb + kb, ldsB + wbase);
    gload_lds16(B + (n0 + 64 + sr) * ldb + kb, ldsB + 2048 + wbase);
    __syncthreads();
    const short* pa = ldsA + ((wr * (TM / 2) + (lane & 15)) * 32) + ((lane >> 4) << 3);
    const short* pb = ldsB + ((wc << 6) + (lane & 15)) * 32 + ((lane >> 4) << 3);
    s8v af[MF], bfr[4];
#pragma unroll
    for (int m = 0; m < MF; ++m) af[m] = *(const s8v*)(pa + m * 512);
#pragma unroll
    for (int n = 0; n < 4; ++n) bfr[n] = *(const s8v*)(pb + n * 512);
#pragma unroll
    for (int m = 0; m < MF; ++m)
#pragma unroll
      for (int n = 0; n < 4; ++n)
        acc[m][n] = __builtin_amdgcn_mfma_f32_16x16x32_bf16(af[m], bfr[n], acc[m][n], 0, 0, 0);
    __syncthreads();
  }

  // ---------------- epilogue via LDS transpose ----------------
  const int cb = (wc << 6) + (lane & 15);
  const int rl = t >> 3;            // read-side local row 0..31
  const int c0 = (t & 7) << 4;      // read-side col base (16 floats)
#pragma unroll
  for (int m = 0; m < MF; ++m) {
    __syncthreads();
#pragma unroll
    for (int n = 0; n < 4; ++n) {
      int c = cb + n * 16;
#pragma unroll
      for (int j = 0; j < 4; ++j) {
        int rloc = (wr << 4) + ((lane >> 4) << 2) + j;
        S[rloc * ESTRIDE + c] = acc[m][n][j];
      }
    }
    __syncthreads();
    const int r = m0 + (rl >> 4) * (TM / 2) + m * 16 + (rl & 15);
    const int colg = n0 + c0;
    float v[16];
#pragma unroll
    for (int i = 0; i < 4; ++i) {
      float4 q4 = *(const float4*)(S + rl * ESTRIDE + c0 + i * 4);
      v[4 * i] = q4.x; v[4 * i + 1] = q4.y; v[4 * i + 2] = q4.z; v[4 * i + 3] = q4.w;
    }
    if (EPI == 0) {
#pragma unroll
      for (int i = 0; i < 4; ++i) {
        float4 b4 = *(const float4*)(bias + colg + i * 4);
        float4 o4 = make_float4(v[4 * i] + b4.x, v[4 * i + 1] + b4.y,
                                v[4 * i + 2] + b4.z, v[4 * i + 3] + b4.w);
        *(float4*)(Xres + (size_t)r * DIM + colg + i * 4) = o4;
      }
    } else if (EPI == 1) {
      if (r < Mlim) {
        const int b = colg / DIM, d0 = colg - b * DIM;
        const float br = bias[r];
        const size_t base = (size_t)b * (PATCHES * DIM) + (size_t)r * DIM + d0;
        float xn[16];
#pragma unroll
        for (int i = 0; i < 4; ++i) {
          float4 g4 = *(const float4*)(gamma + d0 + i * 4);
          float4 x4 = *(const float4*)(Xres + base + i * 4);
          x4.x += g4.x * (v[4 * i] + br);
          x4.y += g4.y * (v[4 * i + 1] + br);
          x4.z += g4.z * (v[4 * i + 2] + br);
          x4.w += g4.w * (v[4 * i + 3] + br);
          *(float4*)(Xres + base + i * 4) = x4;
          xn[4 * i] = x4.x; xn[4 * i + 1] = x4.y; xn[4 * i + 2] = x4.z; xn[4 * i + 3] = x4.w;
        }
#pragma unroll
        for (int h = 0; h < 2; ++h) {
          s8v y;
#pragma unroll
          for (int k = 0; k < 8; ++k) {
            int d = d0 + h * 8 + k;
            y[k] = f2bf(xn[h * 8 + k] * n2a[d] + n2b[d]);
          }
          *(s8v*)(OutB + base + h * 8) = y;
        }
      }
    } else if (EPI == 2) {
#pragma unroll
      for (int h = 0; h < 2; ++h) {
        s8v y;
#pragma unroll
        for (int k = 0; k < 8; ++k) {
          float xg = v[h * 8 + k] + bias[colg + h * 8 + k];
          y[k] = f2bf(gelu_f(xg));
        }
        *(s8v*)(OutB + (size_t)r * HID + colg + h * 8) = y;
      }
    } else {
#pragma unroll
      for (int i = 0; i < 4; ++i) {
        float4 b4 = *(const float4*)(bias + colg + i * 4);
        float4 g4 = *(const float4*)(gamma + colg + i * 4);
        float4 x4 = *(const float4*)(Xres + (size_t)r * DIM + colg + i * 4);
        x4.x += g4.x * (v[4 * i] + b4.x);
        x4.y += g4.y * (v[4 * i + 1] + b4.y);
        x4.z += g4.z * (v[4 * i + 2] + b4.z);
        x4.w += g4.w * (v[4 * i + 3] + b4.w);
        *(float4*)(Xres + (size_t)r * DIM + colg + i * 4) = x4;
      }
    }
  }
}

// ---------------- final affine norm + mean pool ----------------
__global__ __launch_bounds__(384)
void poolnorm(const float* __restrict__ X, const float* __restrict__ na,
              const float* __restrict__ nb, float* __restrict__ pooled) {
  int b = blockIdx.x, d = threadIdx.x;
  const float* p = X + b * (PATCHES * DIM) + d;
  float s = 0.f;
  for (int i = 0; i < PATCHES; ++i) s += p[i * DIM];
  pooled[b * DIM + d] = (s * (1.0f / 196.0f)) * na[d] + nb[d];
}

// ---------------- head: out[b,n] = pooled[b,:] . Whq[n,:] + hb[n] (fp32) ----------------
__global__ __launch_bounds__(256)
void head_k(const float* __restrict__ pooled, const float* __restrict__ Whq,
            const float* __restrict__ hb, float* __restrict__ out) {
  __shared__ float pl[DIM];
  int b = blockIdx.x, t = threadIdx.x;
  if (t < 192) {
    pl[t] = pooled[b * DIM + t];
    pl[t + 192] = pooled[b * DIM + t + 192];
  }
  __syncthreads();
  for (int n = t; n < 1000; n += 256) {
    const float4* w = (const float4*)(Whq + n * DIM);
    float s = 0.f;
#pragma unroll 4
    for (int i = 0; i < DIM / 4; ++i) {
      float4 wv = w[i];
      s += pl[4 * i] * wv.x + pl[4 * i + 1] * wv.y + pl[4 * i + 2] * wv.z + pl[4 * i + 3] * wv.w;
    }
    out[b * 1000 + n] = s + hb[n];
  }
}

extern "C" void kernel_launch(void* const* d_in, const int* in_sizes, int n_in,
                              void* d_out, int out_size, void* d_ws, size_t ws_size,
                              hipStream_t stream) {
  const float* x       = (const float*)d_in[0];
  const float* conv_w  = (const float*)d_in[1];
  const float* conv_b  = (const float*)d_in[2];
  const float* norm1_a = (const float*)d_in[3];
  const float* norm1_b = (const float*)d_in[4];
  const float* attn_w  = (const float*)d_in[5];
  const float* attn_b  = (const float*)d_in[6];
  const float* gamma1  = (const float*)d_in[7];
  const float* norm2_a = (const float*)d_in[8];
  const float* norm2_b = (const float*)d_in[9];
  const float* mlp_w1  = (const float*)d_in[10];
  const float* mlp_b1  = (const float*)d_in[11];
  const float* mlp_w2  = (const float*)d_in[12];
  const float* mlp_b2  = (const float*)d_in[13];
  const float* gamma2  = (const float*)d_in[14];
  const float* norm_a  = (const float*)d_in[15];
  const float* norm_b  = (const float*)d_in[16];
  const float* head_w  = (const float*)d_in[17];
  const float* head_b  = (const float*)d_in[18];
  (void)in_sizes; (void)n_in; (void)out_size; (void)ws_size;

  char* ws = (char*)d_ws;
  size_t off = 0;
  auto alloc = [&](size_t bytes) {
    off = (off + 255) & ~(size_t)255;
    void* p = ws + off;
    off += bytes;
    return p;
  };
  unsigned* scales = (unsigned*)alloc(74 * 4);
  short* conv_wq = (short*)alloc((size_t)DIM * 768 * 2);
  short* attn_wq = (short*)alloc((size_t)NBLK * PATCHES * NPAD * 2);
  short* w1q     = (short*)alloc((size_t)NBLK * HID * DIM * 2);
  short* w2q     = (short*)alloc((size_t)NBLK * DIM * HID * 2);
  float* headq   = (float*)alloc((size_t)1000 * DIM * 4);
  float* X       = (float*)alloc((size_t)XELEMS * 4);
  short* Yt      = (short*)alloc((size_t)BDCOLS * NPAD * 2);
  short* Y2      = (short*)alloc((size_t)XELEMS * 2);
  short* H       = (short*)alloc((size_t)XROWS * HID * 2);
  float* pooled  = (float*)alloc((size_t)64 * DIM * 4);
  short* Xa = H;  // alias: im2col buffer [12544][768] bf16, dead before H is first written

  hipMemsetAsync(scales, 0, 74 * 4, stream);
  // scale slots: [0]=conv, [1]=head, [2..25]=attn, [26..49]=w1, [50..73]=w2
  absmax_k<<<16, 256, 0, stream>>>(conv_w, DIM * 768, 16, scales + 0);
  absmax_k<<<16, 256, 0, stream>>>(head_w, 1000 * DIM, 16, scales + 1);
  absmax_k<<<NBLK * 4, 256, 0, stream>>>(attn_w, PATCHES * PATCHES, 4, scales + 2);
  absmax_k<<<NBLK * 16, 256, 0, stream>>>(mlp_w1, HID * DIM, 16, scales + 26);
  absmax_k<<<NBLK * 16, 256, 0, stream>>>(mlp_w2, DIM * HID, 16, scales + 50);

  quant_w<<<(DIM * 768) / 256, 256, 0, stream>>>(conv_w, conv_wq, scales + 0, DIM * 768, DIM * 768);
  quant_w<<<(NBLK * HID * DIM) / 256, 256, 0, stream>>>(mlp_w1, w1q, scales + 26, HID * DIM, NBLK * HID * DIM);
  quant_w<<<(NBLK * HID * DIM) / 256, 256, 0, stream>>>(mlp_w2, w2q, scales + 50, DIM * HID, NBLK * DIM * HID);
  quant_attn<<<(NBLK * PATCHES * NPAD) / 256, 256, 0, stream>>>(attn_w, attn_wq, scales + 2);
  quant_head<<<(1000 * DIM + 255) / 256, 256, 0, stream>>>(head_w, headq, scales + 1);

  im2col_k<<<(XROWS * 768 / 4) / 256, 256, 0, stream>>>(x, Xa);
  gemm2<0, 64><<<dim3(3, 196), 256, 0, stream>>>(Xa, 768, XROWS, conv_wq, 768, 768,
                                                 X, nullptr, conv_b, nullptr, nullptr, nullptr);

  for (int blk = 0; blk < NBLK; ++blk) {
    normcast_t<<<dim3(BDCOLS / 64, 7), 256, 0, stream>>>(X, norm1_a + blk * DIM,
                                                         norm1_b + blk * DIM, Yt);
    gemm2<1, 64><<<dim3(BDCOLS / 128, 4), 256, 0, stream>>>(
        attn_wq + blk * PATCHES * NPAD, NPAD, PATCHES, Yt, NPAD, NPAD,
        X, Y2, attn_b + blk * PATCHES, gamma1 + blk * DIM,
        norm2_a + blk * DIM, norm2_b + blk * DIM);
    gemm2<2, 128><<<dim3(HID / 128, XROWS / 128), 256, 0, stream>>>(
        Y2, DIM, XROWS, w1q + (size_t)blk * HID * DIM, DIM, DIM,
        nullptr, H, mlp_b1 + blk * HID, nullptr, nullptr, nullptr);
    gemm2<3, 64><<<dim3(DIM / 128, XROWS / 64), 256, 0, stream>>>(
        H, HID, XROWS, w2q + (size_t)blk * DIM * HID, HID, HID,
        X, nullptr, mlp_b2 + blk * DIM, gamma2 + blk * DIM, nullptr, nullptr);
  }

  poolnorm<<<64, 384, 0, stream>>>(X, norm_a, norm_b, pooled);
  head_k<<<64, 256, 0, stream>>>(pooled, headq, head_b, (float*)d_out);
}

// Round 3
// 2860.985 us; speedup vs baseline: 1.1338x; 1.0617x over previous
//
#include <hip/hip_runtime.h>

#define DIM 384
#define PATCHES 196
#define HID 1536
#define NBLK 24
#define NPAD 224                    // K-padded patch count for attn GEMM
#define XROWS (64 * PATCHES)        // 12544
#define BDCOLS (64 * DIM)           // 24576
#define XELEMS (XROWS * DIM)        // 4816896
#define ESTRIDE 132                 // epilogue LDS stage row stride (floats)

typedef __attribute__((ext_vector_type(8))) short s8v;
typedef __attribute__((ext_vector_type(4))) float f4v;

__device__ __forceinline__ short f2bf(float f) {
  unsigned u = __float_as_uint(f);
  u += 0x7FFFu + ((u >> 16) & 1u);   // RNE f32 -> bf16
  return (short)(u >> 16);
}

__device__ __forceinline__ float gelu_f(float x) {
  float u2 = 1.5957691216f * (x + 0.044715f * x * x * x);
  return x / (1.0f + __expf(-u2));
}

__device__ __forceinline__ void gload_lds16(const short* g, short* l) {
  __builtin_amdgcn_global_load_lds((const __attribute__((address_space(1))) void*)g,
                                   (__attribute__((address_space(3))) void*)l, 16, 0, 0);
}

// ---------------- absmax (per-tensor) ----------------
__global__ __launch_bounds__(256)
void absmax_k(const float* __restrict__ src, int per, int blocks_per,
              unsigned* __restrict__ out) {
  int tens = blockIdx.x / blocks_per;
  int sl = blockIdx.x - tens * blocks_per;
  const float* p = src + (long)tens * per;
  float m = 0.f;
  for (int i = sl * 256 + threadIdx.x; i < per; i += blocks_per * 256)
    m = fmaxf(m, fabsf(p[i]));
  __shared__ float red[256];
  red[threadIdx.x] = m;
  __syncthreads();
  for (int s = 128; s > 0; s >>= 1) {
    if ((int)threadIdx.x < s) red[threadIdx.x] = fmaxf(red[threadIdx.x], red[threadIdx.x + s]);
    __syncthreads();
  }
  if (threadIdx.x == 0) atomicMax(out + tens, __float_as_uint(red[0]));
}

// ---------------- quantize (fake-quant, bit-exact fq, then bf16 store) ----------------
__global__ __launch_bounds__(256)
void quant_w(const float* __restrict__ w, short* __restrict__ q,
             const unsigned* __restrict__ sc, int per, int total) {
  int i = blockIdx.x * 256 + threadIdx.x;
  if (i >= total) return;
  int tens = i / per;
  float s = __uint_as_float(sc[tens]) / 127.0f + 1e-8f;
  float v = rintf(w[i] / s);
  v = fminf(fmaxf(v, -128.0f), 127.0f) * s;
  q[i] = f2bf(v);
}

__global__ __launch_bounds__(256)
void quant_attn(const float* __restrict__ w, short* __restrict__ q,
                const unsigned* __restrict__ sc) {
  int i = blockIdx.x * 256 + threadIdx.x;       // over 24*196*224
  if (i >= NBLK * PATCHES * NPAD) return;
  int col = i % NPAD;
  int rt = i / NPAD;
  int row = rt % PATCHES;
  int tens = rt / PATCHES;
  float outv = 0.f;
  if (col < PATCHES) {
    float s = __uint_as_float(sc[tens]) / 127.0f + 1e-8f;
    float v = rintf(w[tens * PATCHES * PATCHES + row * PATCHES + col] / s);
    outv = fminf(fmaxf(v, -128.0f), 127.0f) * s;
  }
  q[i] = f2bf(outv);
}

__global__ __launch_bounds__(256)
void quant_head(const float* __restrict__ w, float* __restrict__ q,
                const unsigned* __restrict__ sc) {
  int i = blockIdx.x * 256 + threadIdx.x;
  if (i >= 1000 * DIM) return;
  float s = __uint_as_float(sc[0]) / 127.0f + 1e-8f;
  float v = rintf(w[i] / s);
  q[i] = fminf(fmaxf(v, -128.0f), 127.0f) * s;
}

// ---------------- im2col + bf16 cast (stride-16 16x16 patches: no overlap) ----------------
__global__ __launch_bounds__(256)
void im2col_k(const float* __restrict__ x, short* __restrict__ Xa) {
  int idx = blockIdx.x * 256 + threadIdx.x;     // each handles 4 elems
  if (idx >= XROWS * 768 / 4) return;
  int e = idx << 2;
  int r = e / 768, k = e - r * 768;
  int b = r / PATCHES, p = r - b * PATCHES;
  int c = k >> 8, rem = k & 255, ii = rem >> 4, j = rem & 15;
  int ph = p / 14, pw = p - ph * 14;
  const float4 v = *(const float4*)(x + (b * 3 + c) * 50176 + (ph * 16 + ii) * 224 + pw * 16 + j);
  short2* o = (short2*)(Xa + e);
  o[0] = make_short2(f2bf(v.x), f2bf(v.y));
  o[1] = make_short2(f2bf(v.z), f2bf(v.w));
}

// ---------------- norm1 + cast + transpose: Yt[(b,d)][p] = bf16(X[b,p,d]*a+b), p-padded to 224 ----
__global__ __launch_bounds__(256)
void normcast_t(const float* __restrict__ X, const float* __restrict__ a1,
                const float* __restrict__ b1, short* __restrict__ Yt) {
  __shared__ short lds[32][72];
  const int t = threadIdx.x;
  const int p0 = blockIdx.y << 5, c0 = blockIdx.x << 6;
  const int cl = t & 63, pl = t >> 6;
  const int c = c0 + cl;
  const int b = c / DIM, d = c - b * DIM;
  const float av = a1[d], bv = b1[d];
#pragma unroll
  for (int i = 0; i < 8; ++i) {
    int p = p0 + pl + (i << 2);
    float xv = 0.f;
    if (p < PATCHES) xv = X[b * (PATCHES * DIM) + p * DIM + d] * av + bv;
    lds[pl + (i << 2)][cl] = f2bf(xv);
  }
  __syncthreads();
  const int r2 = t >> 2, q2 = t & 3;
  short2* o = (short2*)(Yt + (c0 + r2) * NPAD + p0);
#pragma unroll
  for (int i = 0; i < 4; ++i) {
    int k = q2 + (i << 2);
    short2 v;
    v.x = lds[2 * k][r2];
    v.y = lds[2 * k + 1][r2];
    o[k] = v;
  }
}

// ---------------- GEMM C = A * B^T, 2-phase double-buffered pipeline ----------------
// A [M][lda] bf16, B [N][ldb] bf16, both K-contiguous. Tile TM x 128, 4 waves.
// K-loop: raw s_barrier + counted waitcnt (T3 minimum-2-phase recipe): issue next
// tile's global_load_lds BEFORE current tile's ds_read+MFMA; vmcnt(0) drains at
// iter end so load latency hides under compute. Staging addresses hoisted.
// EPI 0: conv   -> X[r*384+c] = acc + bias[c]
// EPI 1: attn   -> xn = X + g1[d]*(acc + bias[r]); X = xn; Y2 = bf16(xn*n2a+n2b)
// EPI 2: mlp1   -> H[r*1536+c] = bf16(gelu(acc + bias[c]))
// EPI 3: mlp2   -> X[r*384+c] += g2[c]*(acc + bias[c])
template <int EPI, int TM>
__global__ __launch_bounds__(256)
void gemm3(const short* __restrict__ A, int lda, int Mlim,
           const short* __restrict__ B, int ldb, int K,
           float* __restrict__ Xres, short* __restrict__ OutB,
           const float* __restrict__ bias, const float* __restrict__ gamma,
           const float* __restrict__ n2a, const float* __restrict__ n2b) {
  constexpr int MF = TM / 32;                    // m-fragments per wave
  constexpr int HA = TM / 64;                    // A staging halves
  constexpr int TILE_SHORTS = (TM + 128) * 32;   // one double-buffer slot
  constexpr int LDS_BYTES = (2 * TILE_SHORTS * 2 > 32 * ESTRIDE * 4)
                                ? 2 * TILE_SHORTS * 2 : 32 * ESTRIDE * 4;
  __shared__ char smem[LDS_BYTES];
  short* buf0 = (short*)smem;
  float* S = (float*)smem;

  const int t = threadIdx.x;
  const int lane = t & 63;
  const int wid = t >> 6;
  const int wr = wid >> 1, wc = wid & 1;

  // XCD-aware bijective block swizzle (m204): blocks sharing A-rows -> same XCD L2
  const int gx = gridDim.x;
  const int nwg = gx * gridDim.y;
  const int orig = blockIdx.y * gx + blockIdx.x;
  const int q = nwg >> 3, rm = nwg & 7;
  const int xc = orig & 7, jj = orig >> 3;
  const int wg = (xc < rm ? xc * (q + 1) : rm * (q + 1) + (xc - rm) * q) + jj;
  const int bx = wg % gx, by = wg / gx;
  const int m0 = by * TM, n0 = bx * 128;

  f4v acc[MF][4];
#pragma unroll
  for (int m = 0; m < MF; ++m)
#pragma unroll
    for (int n = 0; n < 4; ++n) acc[m][n] = (f4v){0.f, 0.f, 0.f, 0.f};

  // ---- hoisted staging addresses (loop-invariant; only +kt*32 varies) ----
  const int sr = t >> 2;            // staging row within 64-row half
  const int scol = (t & 3) << 3;    // staging col (x8 bf16)
  const int wbase = (t & ~63) * 8;  // LDS wave base in shorts (HW adds lane*16B)
  const short* ga[HA];
#pragma unroll
  for (int h = 0; h < HA; ++h) {
    int r = m0 + h * 64 + sr;
    if (r >= Mlim) r = Mlim - 1;
    ga[h] = A + (size_t)r * lda + scol;
  }
  const short* gb0 = B + (size_t)(n0 + sr) * ldb + scol;
  const short* gb1 = B + (size_t)(n0 + 64 + sr) * ldb + scol;
  short* lA = buf0 + wbase;
  short* lB = buf0 + TM * 32 + wbase;

  auto stage = [&](int cur, int kt) {
    const int koff = kt << 5;
    const int boff = cur * TILE_SHORTS;
#pragma unroll
    for (int h = 0; h < HA; ++h) gload_lds16(ga[h] + koff, lA + boff + h * 2048);
    gload_lds16(gb0 + koff, lB + boff);
    gload_lds16(gb1 + koff, lB + boff + 2048);
  };

  const int paoff = (wr * (TM / 2) + (lane & 15)) * 32 + ((lane >> 4) << 3);
  const int pboff = TM * 32 + ((wc << 6) + (lane & 15)) * 32 + ((lane >> 4) << 3);

  const int nk = K >> 5;
  stage(0, 0);
  asm volatile("s_waitcnt vmcnt(0)" ::: "memory");
  __builtin_amdgcn_s_barrier();
  int cur = 0;
  for (int kt = 0; kt < nk; ++kt) {
    if (kt + 1 < nk) stage(cur ^ 1, kt + 1);     // prefetch overlaps this tile's compute
    const short* base = buf0 + cur * TILE_SHORTS;
    s8v af[MF], bfr[4];
#pragma unroll
    for (int m = 0; m < MF; ++m) af[m] = *(const s8v*)(base + paoff + m * 512);
#pragma unroll
    for (int n = 0; n < 4; ++n) bfr[n] = *(const s8v*)(base + pboff + n * 512);
    asm volatile("s_waitcnt lgkmcnt(0)" ::: "memory");
    __builtin_amdgcn_sched_barrier(0);           // rule #18: pin MFMA after lgkmcnt
#pragma unroll
    for (int m = 0; m < MF; ++m)
#pragma unroll
      for (int n = 0; n < 4; ++n)
        acc[m][n] = __builtin_amdgcn_mfma_f32_16x16x32_bf16(af[m], bfr[n], acc[m][n], 0, 0, 0);
    asm volatile("s_waitcnt vmcnt(0)" ::: "memory");
    __builtin_amdgcn_s_barrier();
    cur ^= 1;
  }

  // ---------------- epilogue via LDS transpose ----------------
  const int cb = (wc << 6) + (lane & 15);
  const int rl = t >> 3;            // read-side local row 0..31
  const int c0 = (t & 7) << 4;      // read-side col base (16 floats)
#pragma unroll
  for (int m = 0; m < MF; ++m) {
    __syncthreads();
#pragma unroll
    for (int n = 0; n < 4; ++n) {
      int c = cb + n * 16;
#pragma unroll
      for (int j = 0; j < 4; ++j) {
        int rloc = (wr << 4) + ((lane >> 4) << 2) + j;
        S[rloc * ESTRIDE + c] = acc[m][n][j];
      }
    }
    __syncthreads();
    const int r = m0 + (rl >> 4) * (TM / 2) + m * 16 + (rl & 15);
    const int colg = n0 + c0;
    float v[16];
#pragma unroll
    for (int i = 0; i < 4; ++i) {
      float4 q4 = *(const float4*)(S + rl * ESTRIDE + c0 + i * 4);
      v[4 * i] = q4.x; v[4 * i + 1] = q4.y; v[4 * i + 2] = q4.z; v[4 * i + 3] = q4.w;
    }
    if (EPI == 0) {
#pragma unroll
      for (int i = 0; i < 4; ++i) {
        float4 b4 = *(const float4*)(bias + colg + i * 4);
        float4 o4 = make_float4(v[4 * i] + b4.x, v[4 * i + 1] + b4.y,
                                v[4 * i + 2] + b4.z, v[4 * i + 3] + b4.w);
        *(float4*)(Xres + (size_t)r * DIM + colg + i * 4) = o4;
      }
    } else if (EPI == 1) {
      if (r < Mlim) {
        const int b = colg / DIM, d0 = colg - b * DIM;
        const float br = bias[r];
        const size_t base2 = (size_t)b * (PATCHES * DIM) + (size_t)r * DIM + d0;
        float xn[16];
#pragma unroll
        for (int i = 0; i < 4; ++i) {
          float4 g4 = *(const float4*)(gamma + d0 + i * 4);
          float4 x4 = *(const float4*)(Xres + base2 + i * 4);
          x4.x += g4.x * (v[4 * i] + br);
          x4.y += g4.y * (v[4 * i + 1] + br);
          x4.z += g4.z * (v[4 * i + 2] + br);
          x4.w += g4.w * (v[4 * i + 3] + br);
          *(float4*)(Xres + base2 + i * 4) = x4;
          xn[4 * i] = x4.x; xn[4 * i + 1] = x4.y; xn[4 * i + 2] = x4.z; xn[4 * i + 3] = x4.w;
        }
#pragma unroll
        for (int h = 0; h < 2; ++h) {
          s8v y;
#pragma unroll
          for (int k = 0; k < 8; ++k) {
            int d = d0 + h * 8 + k;
            y[k] = f2bf(xn[h * 8 + k] * n2a[d] + n2b[d]);
          }
          *(s8v*)(OutB + base2 + h * 8) = y;
        }
      }
    } else if (EPI == 2) {
#pragma unroll
      for (int h = 0; h < 2; ++h) {
        s8v y;
#pragma unroll
        for (int k = 0; k < 8; ++k) {
          float xg = v[h * 8 + k] + bias[colg + h * 8 + k];
          y[k] = f2bf(gelu_f(xg));
        }
        *(s8v*)(OutB + (size_t)r * HID + colg + h * 8) = y;
      }
    } else {
#pragma unroll
      for (int i = 0; i < 4; ++i) {
        float4 b4 = *(const float4*)(bias + colg + i * 4);
        float4 g4 = *(const float4*)(gamma + colg + i * 4);
        float4 x4 = *(const float4*)(Xres + (size_t)r * DIM + colg + i * 4);
        x4.x += g4.x * (v[4 * i] + b4.x);
        x4.y += g4.y * (v[4 * i + 1] + b4.y);
        x4.z += g4.z * (v[4 * i + 2] + b4.z);
        x4.w += g4.w * (v[4 * i + 3] + b4.w);
        *(float4*)(Xres + (size_t)r * DIM + colg + i * 4) = x4;
      }
    }
  }
}

// ---------------- final affine norm + mean pool ----------------
__global__ __launch_bounds__(384)
void poolnorm(const float* __restrict__ X, const float* __restrict__ na,
              const float* __restrict__ nb, float* __restrict__ pooled) {
  int b = blockIdx.x, d = threadIdx.x;
  const float* p = X + b * (PATCHES * DIM) + d;
  float s = 0.f;
  for (int i = 0; i < PATCHES; ++i) s += p[i * DIM];
  pooled[b * DIM + d] = (s * (1.0f / 196.0f)) * na[d] + nb[d];
}

// ---------------- head: out[b,n] = pooled[b,:] . Whq[n,:] + hb[n] (fp32) ----------------
__global__ __launch_bounds__(256)
void head_k(const float* __restrict__ pooled, const float* __restrict__ Whq,
            const float* __restrict__ hb, float* __restrict__ out) {
  __shared__ float pl[DIM];
  int b = blockIdx.x, t = threadIdx.x;
  if (t < 192) {
    pl[t] = pooled[b * DIM + t];
    pl[t + 192] = pooled[b * DIM + t + 192];
  }
  __syncthreads();
  for (int n = t; n < 1000; n += 256) {
    const float4* w = (const float4*)(Whq + n * DIM);
    float s = 0.f;
#pragma unroll 4
    for (int i = 0; i < DIM / 4; ++i) {
      float4 wv = w[i];
      s += pl[4 * i] * wv.x + pl[4 * i + 1] * wv.y + pl[4 * i + 2] * wv.z + pl[4 * i + 3] * wv.w;
    }
    out[b * 1000 + n] = s + hb[n];
  }
}

extern "C" void kernel_launch(void* const* d_in, const int* in_sizes, int n_in,
                              void* d_out, int out_size, void* d_ws, size_t ws_size,
                              hipStream_t stream) {
  const float* x       = (const float*)d_in[0];
  const float* conv_w  = (const float*)d_in[1];
  const float* conv_b  = (const float*)d_in[2];
  const float* norm1_a = (const float*)d_in[3];
  const float* norm1_b = (const float*)d_in[4];
  const float* attn_w  = (const float*)d_in[5];
  const float* attn_b  = (const float*)d_in[6];
  const float* gamma1  = (const float*)d_in[7];
  const float* norm2_a = (const float*)d_in[8];
  const float* norm2_b = (const float*)d_in[9];
  const float* mlp_w1  = (const float*)d_in[10];
  const float* mlp_b1  = (const float*)d_in[11];
  const float* mlp_w2  = (const float*)d_in[12];
  const float* mlp_b2  = (const float*)d_in[13];
  const float* gamma2  = (const float*)d_in[14];
  const float* norm_a  = (const float*)d_in[15];
  const float* norm_b  = (const float*)d_in[16];
  const float* head_w  = (const float*)d_in[17];
  const float* head_b  = (const float*)d_in[18];
  (void)in_sizes; (void)n_in; (void)out_size; (void)ws_size;

  char* ws = (char*)d_ws;
  size_t off = 0;
  auto alloc = [&](size_t bytes) {
    off = (off + 255) & ~(size_t)255;
    void* p = ws + off;
    off += bytes;
    return p;
  };
  unsigned* scales = (unsigned*)alloc(74 * 4);
  short* conv_wq = (short*)alloc((size_t)DIM * 768 * 2);
  short* attn_wq = (short*)alloc((size_t)NBLK * PATCHES * NPAD * 2);
  short* w1q     = (short*)alloc((size_t)NBLK * HID * DIM * 2);
  short* w2q     = (short*)alloc((size_t)NBLK * DIM * HID * 2);
  float* headq   = (float*)alloc((size_t)1000 * DIM * 4);
  float* X       = (float*)alloc((size_t)XELEMS * 4);
  short* Yt      = (short*)alloc((size_t)BDCOLS * NPAD * 2);
  short* Y2      = (short*)alloc((size_t)XELEMS * 2);
  short* H       = (short*)alloc((size_t)XROWS * HID * 2);
  float* pooled  = (float*)alloc((size_t)64 * DIM * 4);
  short* Xa = H;  // alias: im2col buffer [12544][768] bf16, dead before H is first written

  hipMemsetAsync(scales, 0, 74 * 4, stream);
  // scale slots: [0]=conv, [1]=head, [2..25]=attn, [26..49]=w1, [50..73]=w2
  absmax_k<<<16, 256, 0, stream>>>(conv_w, DIM * 768, 16, scales + 0);
  absmax_k<<<16, 256, 0, stream>>>(head_w, 1000 * DIM, 16, scales + 1);
  absmax_k<<<NBLK * 4, 256, 0, stream>>>(attn_w, PATCHES * PATCHES, 4, scales + 2);
  absmax_k<<<NBLK * 16, 256, 0, stream>>>(mlp_w1, HID * DIM, 16, scales + 26);
  absmax_k<<<NBLK * 16, 256, 0, stream>>>(mlp_w2, DIM * HID, 16, scales + 50);

  quant_w<<<(DIM * 768) / 256, 256, 0, stream>>>(conv_w, conv_wq, scales + 0, DIM * 768, DIM * 768);
  quant_w<<<(NBLK * HID * DIM) / 256, 256, 0, stream>>>(mlp_w1, w1q, scales + 26, HID * DIM, NBLK * HID * DIM);
  quant_w<<<(NBLK * HID * DIM) / 256, 256, 0, stream>>>(mlp_w2, w2q, scales + 50, DIM * HID, NBLK * DIM * HID);
  quant_attn<<<(NBLK * PATCHES * NPAD) / 256, 256, 0, stream>>>(attn_w, attn_wq, scales + 2);
  quant_head<<<(1000 * DIM + 255) / 256, 256, 0, stream>>>(head_w, headq, scales + 1);

  im2col_k<<<(XROWS * 768 / 4) / 256, 256, 0, stream>>>(x, Xa);
  gemm3<0, 64><<<dim3(3, 196), 256, 0, stream>>>(Xa, 768, XROWS, conv_wq, 768, 768,
                                                 X, nullptr, conv_b, nullptr, nullptr, nullptr);

  for (int blk = 0; blk < NBLK; ++blk) {
    normcast_t<<<dim3(BDCOLS / 64, 7), 256, 0, stream>>>(X, norm1_a + blk * DIM,
                                                         norm1_b + blk * DIM, Yt);
    gemm3<1, 64><<<dim3(BDCOLS / 128, 4), 256, 0, stream>>>(
        attn_wq + blk * PATCHES * NPAD, NPAD, PATCHES, Yt, NPAD, NPAD,
        X, Y2, attn_b + blk * PATCHES, gamma1 + blk * DIM,
        norm2_a + blk * DIM, norm2_b + blk * DIM);
    gemm3<2, 128><<<dim3(HID / 128, XROWS / 128), 256, 0, stream>>>(
        Y2, DIM, XROWS, w1q + (size_t)blk * HID * DIM, DIM, DIM,
        nullptr, H, mlp_b1 + blk * HID, nullptr, nullptr, nullptr);
    gemm3<3, 64><<<dim3(DIM / 128, XROWS / 64), 256, 0, stream>>>(
        H, HID, XROWS, w2q + (size_t)blk * DIM * HID, HID, HID,
        X, nullptr, mlp_b2 + blk * DIM, gamma2 + blk * DIM, nullptr, nullptr);
  }

  poolnorm<<<64, 384, 0, stream>>>(X, norm_a, norm_b, pooled);
  head_k<<<64, 256, 0, stream>>>(pooled, headq, head_b, (float*)d_out);
}

// Round 4
// 2607.476 us; speedup vs baseline: 1.2440x; 1.0972x over previous
//
#include <hip/hip_runtime.h>

#define DIM 384
#define PATCHES 196
#define HID 1536
#define NBLK 24
#define NPAD 256                    // K-padded patch count for attn GEMM (divisible by 64)
#define XROWS (64 * PATCHES)        // 12544
#define BDCOLS (64 * DIM)           // 24576
#define XELEMS (XROWS * DIM)        // 4816896
#define ESTRIDE 132                 // epilogue LDS stage row stride (floats)

typedef __attribute__((ext_vector_type(8))) short s8v;
typedef __attribute__((ext_vector_type(4))) float f4v;

__device__ __forceinline__ short f2bf(float f) {
  unsigned u = __float_as_uint(f);
  u += 0x7FFFu + ((u >> 16) & 1u);   // RNE f32 -> bf16
  return (short)(u >> 16);
}

__device__ __forceinline__ float gelu_f(float x) {
  float u2 = 1.5957691216f * (x + 0.044715f * x * x * x);
  return x / (1.0f + __expf(-u2));
}

__device__ __forceinline__ void gload_lds16(const short* g, short* l) {
  __builtin_amdgcn_global_load_lds((const __attribute__((address_space(1))) void*)g,
                                   (__attribute__((address_space(3))) void*)l, 16, 0, 0);
}

// ---------------- absmax (per-tensor) ----------------
__global__ __launch_bounds__(256)
void absmax_k(const float* __restrict__ src, int per, int blocks_per,
              unsigned* __restrict__ out) {
  int tens = blockIdx.x / blocks_per;
  int sl = blockIdx.x - tens * blocks_per;
  const float* p = src + (long)tens * per;
  float m = 0.f;
  for (int i = sl * 256 + threadIdx.x; i < per; i += blocks_per * 256)
    m = fmaxf(m, fabsf(p[i]));
  __shared__ float red[256];
  red[threadIdx.x] = m;
  __syncthreads();
  for (int s = 128; s > 0; s >>= 1) {
    if ((int)threadIdx.x < s) red[threadIdx.x] = fmaxf(red[threadIdx.x], red[threadIdx.x + s]);
    __syncthreads();
  }
  if (threadIdx.x == 0) atomicMax(out + tens, __float_as_uint(red[0]));
}

// ---------------- quantize (fake-quant, bit-exact fq, then bf16 store) ----------------
__global__ __launch_bounds__(256)
void quant_w(const float* __restrict__ w, short* __restrict__ q,
             const unsigned* __restrict__ sc, int per, int total) {
  int i = blockIdx.x * 256 + threadIdx.x;
  if (i >= total) return;
  int tens = i / per;
  float s = __uint_as_float(sc[tens]) / 127.0f + 1e-8f;
  float v = rintf(w[i] / s);
  v = fminf(fmaxf(v, -128.0f), 127.0f) * s;
  q[i] = f2bf(v);
}

__global__ __launch_bounds__(256)
void quant_attn(const float* __restrict__ w, short* __restrict__ q,
                const unsigned* __restrict__ sc) {
  int i = blockIdx.x * 256 + threadIdx.x;       // over 24*196*256
  if (i >= NBLK * PATCHES * NPAD) return;
  int col = i % NPAD;
  int rt = i / NPAD;
  int row = rt % PATCHES;
  int tens = rt / PATCHES;
  float outv = 0.f;
  if (col < PATCHES) {
    float s = __uint_as_float(sc[tens]) / 127.0f + 1e-8f;
    float v = rintf(w[tens * PATCHES * PATCHES + row * PATCHES + col] / s);
    outv = fminf(fmaxf(v, -128.0f), 127.0f) * s;
  }
  q[i] = f2bf(outv);
}

__global__ __launch_bounds__(256)
void quant_head(const float* __restrict__ w, float* __restrict__ q,
                const unsigned* __restrict__ sc) {
  int i = blockIdx.x * 256 + threadIdx.x;
  if (i >= 1000 * DIM) return;
  float s = __uint_as_float(sc[0]) / 127.0f + 1e-8f;
  float v = rintf(w[i] / s);
  q[i] = fminf(fmaxf(v, -128.0f), 127.0f) * s;
}

// ---------------- im2col + bf16 cast (stride-16 16x16 patches: no overlap) ----------------
__global__ __launch_bounds__(256)
void im2col_k(const float* __restrict__ x, short* __restrict__ Xa) {
  int idx = blockIdx.x * 256 + threadIdx.x;     // each handles 4 elems
  if (idx >= XROWS * 768 / 4) return;
  int e = idx << 2;
  int r = e / 768, k = e - r * 768;
  int b = r / PATCHES, p = r - b * PATCHES;
  int c = k >> 8, rem = k & 255, ii = rem >> 4, j = rem & 15;
  int ph = p / 14, pw = p - ph * 14;
  const float4 v = *(const float4*)(x + (b * 3 + c) * 50176 + (ph * 16 + ii) * 224 + pw * 16 + j);
  short2* o = (short2*)(Xa + e);
  o[0] = make_short2(f2bf(v.x), f2bf(v.y));
  o[1] = make_short2(f2bf(v.z), f2bf(v.w));
}

// ---------------- GEMM C = A * B^T, BK=64, 2-phase dbuf, T2 XOR-swizzled LDS ----------
// A [M][lda] bf16, B [N][ldb] bf16, K-contiguous. Tile 64x128, 4 waves (2x2).
// LDS tile rows are 64 shorts (128 B). Swizzle (rule #21, both-sides involution):
//   position (row, cg) holds global col-group cg ^ (row&7)  [cg = 16B chunk index 0..7]
//   - write side: global_load_lds dest is LINEAR; the global SOURCE col is permuted.
//   - read side: ds_read addr uses cg' = (ksub*4 + (lane>>4)) ^ (lane&7)  (row&7==lane&7
//     for every fragment since fragment row bases are multiples of 16).
//   => lanes 0-15 spread over all 32 banks (2-way = free) instead of 8-way.
// EPI 0: conv   -> X = acc + bias[c];                     + fused norm1 -> Yt (layer 0)
// EPI 1: attn   -> xn = X + g1*(acc + bias[r]); X = xn;   Y2 = bf16(xn*n2a+n2b)
// EPI 2: mlp1   -> H = bf16(gelu(acc + bias[c]))
// EPI 3: mlp2   -> X += g2*(acc + bias[c]);               + fused norm1 -> Yt (next layer)
template <int EPI>
__global__ __launch_bounds__(256)
void gemm4(const short* __restrict__ A, int lda, int Mlim,
           const short* __restrict__ B, int ldb, int K,
           float* __restrict__ Xres, short* __restrict__ OutB,
           const float* __restrict__ bias, const float* __restrict__ gamma,
           const float* __restrict__ n2a, const float* __restrict__ n2b,
           const float* __restrict__ n1a, const float* __restrict__ n1b,
           short* __restrict__ Yt) {
  constexpr int TILE_SHORTS = 192 * 64;          // A 64x64 + B 128x64
  __shared__ char smem[2 * TILE_SHORTS * 2];     // 49152 B -> 3 blocks/CU
  short* buf0 = (short*)smem;
  float* S = (float*)smem;

  const int t = threadIdx.x;
  const int lane = t & 63;
  const int wid = t >> 6;
  const int wr = wid >> 1, wc = wid & 1;

  // XCD-aware bijective block swizzle (m204)
  const int gx = gridDim.x;
  const int nwg = gx * gridDim.y;
  const int orig = blockIdx.y * gx + blockIdx.x;
  const int q = nwg >> 3, rm = nwg & 7;
  const int xc = orig & 7, jj = orig >> 3;
  const int wg = (xc < rm ? xc * (q + 1) : rm * (q + 1) + (xc - rm) * q) + jj;
  const int bx = wg % gx, by = wg / gx;
  const int m0 = by * 64, n0 = bx * 128;

  f4v acc[2][4];
#pragma unroll
  for (int m = 0; m < 2; ++m)
#pragma unroll
    for (int n = 0; n < 4; ++n) acc[m][n] = (f4v){0.f, 0.f, 0.f, 0.f};

  // ---- staging: thread t <-> LDS slot (row_pos = pass*32 + (t>>3), cg_pos = t&7) ----
  const int srow = t >> 3;
  const int scol = ((t & 7) ^ (srow & 7)) << 3;  // pre-swizzled global col (shorts)
  const short* ga[2];
#pragma unroll
  for (int h = 0; h < 2; ++h) {
    int r = m0 + h * 32 + srow;
    if (r >= Mlim) r = Mlim - 1;
    ga[h] = A + (size_t)r * lda + scol;
  }
  const short* gb[4];
#pragma unroll
  for (int j = 0; j < 4; ++j)
    gb[j] = B + (size_t)(n0 + j * 32 + srow) * ldb + scol;
  short* ldst = buf0 + (t & ~63) * 8;            // wave-uniform base; HW adds lane*16B

  auto stage = [&](int cur, int kt) {
    const int koff = kt << 6;
    const int boff = cur * TILE_SHORTS;
    gload_lds16(ga[0] + koff, ldst + boff);
    gload_lds16(ga[1] + koff, ldst + boff + 2048);
#pragma unroll
    for (int j = 0; j < 4; ++j)
      gload_lds16(gb[j] + koff, ldst + boff + 4096 + j * 2048);
  };

  // ---- swizzled ds_read offsets (shorts) ----
  const int l15 = lane & 15, lk = lane >> 4, l7 = lane & 7;
  int paoff[2], pboff[2];
#pragma unroll
  for (int ks = 0; ks < 2; ++ks) {
    const int cgx = ((ks << 2) + lk) ^ l7;
    paoff[ks] = (wr * 32 + l15) * 64 + (cgx << 3);
    pboff[ks] = 4096 + (wc * 64 + l15) * 64 + (cgx << 3);
  }

  const int nk = K >> 6;
  stage(0, 0);
  asm volatile("s_waitcnt vmcnt(0)" ::: "memory");
  __builtin_amdgcn_s_barrier();
  int cur = 0;
  for (int kt = 0; kt < nk; ++kt) {
    if (kt + 1 < nk) stage(cur ^ 1, kt + 1);     // prefetch overlaps this tile's compute
    const short* base = buf0 + cur * TILE_SHORTS;
    s8v af[2][2], bfr[4][2];
#pragma unroll
    for (int m = 0; m < 2; ++m)
#pragma unroll
      for (int ks = 0; ks < 2; ++ks)
        af[m][ks] = *(const s8v*)(base + paoff[ks] + m * 1024);
#pragma unroll
    for (int n = 0; n < 4; ++n)
#pragma unroll
      for (int ks = 0; ks < 2; ++ks)
        bfr[n][ks] = *(const s8v*)(base + pboff[ks] + n * 1024);
    asm volatile("s_waitcnt lgkmcnt(0)" ::: "memory");
    __builtin_amdgcn_sched_barrier(0);           // rule #18
#pragma unroll
    for (int m = 0; m < 2; ++m)
#pragma unroll
      for (int n = 0; n < 4; ++n)
#pragma unroll
        for (int ks = 0; ks < 2; ++ks)
          acc[m][n] = __builtin_amdgcn_mfma_f32_16x16x32_bf16(af[m][ks], bfr[n][ks], acc[m][n], 0, 0, 0);
    asm volatile("s_waitcnt vmcnt(0)" ::: "memory");
    __builtin_amdgcn_s_barrier();
    cur ^= 1;
  }

  // ---------------- epilogue via LDS transpose ----------------
  const int cb = (wc << 6) + l15;
  const int rl = t >> 3;            // read-side local row 0..31
  const int c0 = (t & 7) << 4;      // read-side col base (16 floats)
#pragma unroll
  for (int m = 0; m < 2; ++m) {
    __syncthreads();
#pragma unroll
    for (int n = 0; n < 4; ++n) {
      int c = cb + n * 16;
#pragma unroll
      for (int j = 0; j < 4; ++j) {
        int rloc = (wr << 4) + (lk << 2) + j;
        S[rloc * ESTRIDE + c] = acc[m][n][j];
      }
    }
    __syncthreads();
    const int r = m0 + (rl >> 4) * 32 + m * 16 + (rl & 15);
    const int colg = n0 + c0;
    float v[16];
#pragma unroll
    for (int i = 0; i < 4; ++i) {
      float4 q4 = *(const float4*)(S + rl * ESTRIDE + c0 + i * 4);
      v[4 * i] = q4.x; v[4 * i + 1] = q4.y; v[4 * i + 2] = q4.z; v[4 * i + 3] = q4.w;
    }
    if (EPI == 0 || EPI == 3) {
      float xn[16];
      if (EPI == 0) {
#pragma unroll
        for (int i = 0; i < 4; ++i) {
          float4 b4 = *(const float4*)(bias + colg + i * 4);
          float4 o4 = make_float4(v[4 * i] + b4.x, v[4 * i + 1] + b4.y,
                                  v[4 * i + 2] + b4.z, v[4 * i + 3] + b4.w);
          *(float4*)(Xres + (size_t)r * DIM + colg + i * 4) = o4;
          xn[4 * i] = o4.x; xn[4 * i + 1] = o4.y; xn[4 * i + 2] = o4.z; xn[4 * i + 3] = o4.w;
        }
      } else {
#pragma unroll
        for (int i = 0; i < 4; ++i) {
          float4 b4 = *(const float4*)(bias + colg + i * 4);
          float4 g4 = *(const float4*)(gamma + colg + i * 4);
          float4 x4 = *(const float4*)(Xres + (size_t)r * DIM + colg + i * 4);
          x4.x += g4.x * (v[4 * i] + b4.x);
          x4.y += g4.y * (v[4 * i + 1] + b4.y);
          x4.z += g4.z * (v[4 * i + 2] + b4.z);
          x4.w += g4.w * (v[4 * i + 3] + b4.w);
          *(float4*)(Xres + (size_t)r * DIM + colg + i * 4) = x4;
          xn[4 * i] = x4.x; xn[4 * i + 1] = x4.y; xn[4 * i + 2] = x4.z; xn[4 * i + 3] = x4.w;
        }
      }
      if (Yt != nullptr) {                       // fused norm1+transpose for next attn
        int bb = r / PATCHES, p = r - bb * PATCHES;
        short* yrow = Yt + ((size_t)(bb * DIM + colg)) * NPAD + p;
#pragma unroll
        for (int i = 0; i < 4; ++i) {
          float4 a4 = *(const float4*)(n1a + colg + i * 4);
          float4 b4 = *(const float4*)(n1b + colg + i * 4);
          yrow[(4 * i + 0) * NPAD] = f2bf(xn[4 * i] * a4.x + b4.x);
          yrow[(4 * i + 1) * NPAD] = f2bf(xn[4 * i + 1] * a4.y + b4.y);
          yrow[(4 * i + 2) * NPAD] = f2bf(xn[4 * i + 2] * a4.z + b4.z);
          yrow[(4 * i + 3) * NPAD] = f2bf(xn[4 * i + 3] * a4.w + b4.w);
        }
      }
    } else if (EPI == 1) {
      if (r < Mlim) {
        const int b = colg / DIM, d0 = colg - b * DIM;
        const float br = bias[r];
        const size_t base2 = (size_t)b * (PATCHES * DIM) + (size_t)r * DIM + d0;
        float xn[16];
#pragma unroll
        for (int i = 0; i < 4; ++i) {
          float4 g4 = *(const float4*)(gamma + d0 + i * 4);
          float4 x4 = *(const float4*)(Xres + base2 + i * 4);
          x4.x += g4.x * (v[4 * i] + br);
          x4.y += g4.y * (v[4 * i + 1] + br);
          x4.z += g4.z * (v[4 * i + 2] + br);
          x4.w += g4.w * (v[4 * i + 3] + br);
          *(float4*)(Xres + base2 + i * 4) = x4;
          xn[4 * i] = x4.x; xn[4 * i + 1] = x4.y; xn[4 * i + 2] = x4.z; xn[4 * i + 3] = x4.w;
        }
#pragma unroll
        for (int h = 0; h < 2; ++h) {
          s8v y;
#pragma unroll
          for (int k = 0; k < 8; ++k) {
            int d = d0 + h * 8 + k;
            y[k] = f2bf(xn[h * 8 + k] * n2a[d] + n2b[d]);
          }
          *(s8v*)(OutB + base2 + h * 8) = y;
        }
      }
    } else {  // EPI == 2
#pragma unroll
      for (int h = 0; h < 2; ++h) {
        s8v y;
#pragma unroll
        for (int k = 0; k < 8; ++k) {
          float xg = v[h * 8 + k] + bias[colg + h * 8 + k];
          y[k] = f2bf(gelu_f(xg));
        }
        *(s8v*)(OutB + (size_t)r * HID + colg + h * 8) = y;
      }
    }
  }
}

// ---------------- final affine norm + mean pool ----------------
__global__ __launch_bounds__(384)
void poolnorm(const float* __restrict__ X, const float* __restrict__ na,
              const float* __restrict__ nb, float* __restrict__ pooled) {
  int b = blockIdx.x, d = threadIdx.x;
  const float* p = X + b * (PATCHES * DIM) + d;
  float s = 0.f;
  for (int i = 0; i < PATCHES; ++i) s += p[i * DIM];
  pooled[b * DIM + d] = (s * (1.0f / 196.0f)) * na[d] + nb[d];
}

// ---------------- head: out[b,n] = pooled[b,:] . Whq[n,:] + hb[n] (fp32) ----------------
__global__ __launch_bounds__(256)
void head_k(const float* __restrict__ pooled, const float* __restrict__ Whq,
            const float* __restrict__ hb, float* __restrict__ out) {
  __shared__ float pl[DIM];
  int b = blockIdx.x, t = threadIdx.x;
  if (t < 192) {
    pl[t] = pooled[b * DIM + t];
    pl[t + 192] = pooled[b * DIM + t + 192];
  }
  __syncthreads();
  for (int n = t; n < 1000; n += 256) {
    const float4* w = (const float4*)(Whq + n * DIM);
    float s = 0.f;
#pragma unroll 4
    for (int i = 0; i < DIM / 4; ++i) {
      float4 wv = w[i];
      s += pl[4 * i] * wv.x + pl[4 * i + 1] * wv.y + pl[4 * i + 2] * wv.z + pl[4 * i + 3] * wv.w;
    }
    out[b * 1000 + n] = s + hb[n];
  }
}

extern "C" void kernel_launch(void* const* d_in, const int* in_sizes, int n_in,
                              void* d_out, int out_size, void* d_ws, size_t ws_size,
                              hipStream_t stream) {
  const float* x       = (const float*)d_in[0];
  const float* conv_w  = (const float*)d_in[1];
  const float* conv_b  = (const float*)d_in[2];
  const float* norm1_a = (const float*)d_in[3];
  const float* norm1_b = (const float*)d_in[4];
  const float* attn_w  = (const float*)d_in[5];
  const float* attn_b  = (const float*)d_in[6];
  const float* gamma1  = (const float*)d_in[7];
  const float* norm2_a = (const float*)d_in[8];
  const float* norm2_b = (const float*)d_in[9];
  const float* mlp_w1  = (const float*)d_in[10];
  const float* mlp_b1  = (const float*)d_in[11];
  const float* mlp_w2  = (const float*)d_in[12];
  const float* mlp_b2  = (const float*)d_in[13];
  const float* gamma2  = (const float*)d_in[14];
  const float* norm_a  = (const float*)d_in[15];
  const float* norm_b  = (const float*)d_in[16];
  const float* head_w  = (const float*)d_in[17];
  const float* head_b  = (const float*)d_in[18];
  (void)in_sizes; (void)n_in; (void)out_size; (void)ws_size;

  char* ws = (char*)d_ws;
  size_t off = 0;
  auto alloc = [&](size_t bytes) {
    off = (off + 255) & ~(size_t)255;
    void* p = ws + off;
    off += bytes;
    return p;
  };
  unsigned* scales = (unsigned*)alloc(74 * 4);
  short* conv_wq = (short*)alloc((size_t)DIM * 768 * 2);
  short* attn_wq = (short*)alloc((size_t)NBLK * PATCHES * NPAD * 2);
  short* w1q     = (short*)alloc((size_t)NBLK * HID * DIM * 2);
  short* w2q     = (short*)alloc((size_t)NBLK * DIM * HID * 2);
  float* headq   = (float*)alloc((size_t)1000 * DIM * 4);
  float* X       = (float*)alloc((size_t)XELEMS * 4);
  short* Yt      = (short*)alloc((size_t)BDCOLS * NPAD * 2);
  short* Y2      = (short*)alloc((size_t)XELEMS * 2);
  short* H       = (short*)alloc((size_t)XROWS * HID * 2);
  float* pooled  = (float*)alloc((size_t)64 * DIM * 4);
  short* Xa = H;  // alias: im2col buffer [12544][768] bf16, dead before H is first written

  hipMemsetAsync(scales, 0, 74 * 4, stream);
  hipMemsetAsync(Yt, 0, (size_t)BDCOLS * NPAD * 2, stream);  // zero K-pad cols (p>=196)
  // scale slots: [0]=conv, [1]=head, [2..25]=attn, [26..49]=w1, [50..73]=w2
  absmax_k<<<16, 256, 0, stream>>>(conv_w, DIM * 768, 16, scales + 0);
  absmax_k<<<16, 256, 0, stream>>>(head_w, 1000 * DIM, 16, scales + 1);
  absmax_k<<<NBLK * 4, 256, 0, stream>>>(attn_w, PATCHES * PATCHES, 4, scales + 2);
  absmax_k<<<NBLK * 16, 256, 0, stream>>>(mlp_w1, HID * DIM, 16, scales + 26);
  absmax_k<<<NBLK * 16, 256, 0, stream>>>(mlp_w2, DIM * HID, 16, scales + 50);

  quant_w<<<(DIM * 768) / 256, 256, 0, stream>>>(conv_w, conv_wq, scales + 0, DIM * 768, DIM * 768);
  quant_w<<<(NBLK * HID * DIM) / 256, 256, 0, stream>>>(mlp_w1, w1q, scales + 26, HID * DIM, NBLK * HID * DIM);
  quant_w<<<(NBLK * HID * DIM) / 256, 256, 0, stream>>>(mlp_w2, w2q, scales + 50, DIM * HID, NBLK * DIM * HID);
  quant_attn<<<(NBLK * PATCHES * NPAD) / 256, 256, 0, stream>>>(attn_w, attn_wq, scales + 2);
  quant_head<<<(1000 * DIM + 255) / 256, 256, 0, stream>>>(head_w, headq, scales + 1);

  im2col_k<<<(XROWS * 768 / 4) / 256, 256, 0, stream>>>(x, Xa);
  // conv epilogue also produces Yt for layer 0 (fused norm1)
  gemm4<0><<<dim3(3, 196), 256, 0, stream>>>(Xa, 768, XROWS, conv_wq, 768, 768,
                                             X, nullptr, conv_b, nullptr, nullptr, nullptr,
                                             norm1_a, norm1_b, Yt);

  for (int blk = 0; blk < NBLK; ++blk) {
    gemm4<1><<<dim3(BDCOLS / 128, 4), 256, 0, stream>>>(
        attn_wq + blk * PATCHES * NPAD, NPAD, PATCHES, Yt, NPAD, NPAD,
        X, Y2, attn_b + blk * PATCHES, gamma1 + blk * DIM,
        norm2_a + blk * DIM, norm2_b + blk * DIM, nullptr, nullptr, nullptr);
    gemm4<2><<<dim3(HID / 128, XROWS / 64), 256, 0, stream>>>(
        Y2, DIM, XROWS, w1q + (size_t)blk * HID * DIM, DIM, DIM,
        nullptr, H, mlp_b1 + blk * HID, nullptr, nullptr, nullptr,
        nullptr, nullptr, nullptr);
    // mlp2 epilogue also produces Yt for layer blk+1 (fused norm1)
    const bool last = (blk == NBLK - 1);
    gemm4<3><<<dim3(DIM / 128, XROWS / 64), 256, 0, stream>>>(
        H, HID, XROWS, w2q + (size_t)blk * DIM * HID, HID, HID,
        X, nullptr, mlp_b2 + blk * DIM, gamma2 + blk * DIM, nullptr, nullptr,
        last ? nullptr : norm1_a + (blk + 1) * DIM,
        last ? nullptr : norm1_b + (blk + 1) * DIM,
        last ? nullptr : Yt);
  }

  poolnorm<<<64, 384, 0, stream>>>(X, norm_a, norm_b, pooled);
  head_k<<<64, 256, 0, stream>>>(pooled, headq, head_b, (float*)d_out);
}